// Round 2
// baseline (192.673 us; speedup 1.0000x reference)
//
#include <hip/hip_runtime.h>

// Problem constants (from reference):
//   e_src: [B=32, T=1024, F=4, C=256] fp32
//   d_src: [B=32, S=256] integer durations in [0, 8)
//   out:   [B=32, S=256, C=256] fp32 segment means (zeros for empty segments)
//
// Structure:
//   Kernel A (32 blocks): per-batch inclusive scan of durations -> clamped
//     (start,end) frame ranges per (b,s) into d_ws.  ~2 us.
//   Kernel B (2048 blocks, 256 thr): one WAVE per phone (4 phones/block).
//     Lane l owns channels 4l..4l+3 and sums the 4 freq bins itself ->
//     no LDS, no __syncthreads, no idle lanes, fully coalesced 16B loads.

#define NB 32
#define NT 1024
#define NF 4
#define NC 256
#define NS 256

__global__ __launch_bounds__(256) void fs2_scan_kernel(
    const int* __restrict__ d_src,   // [B, S]
    int2*      __restrict__ se)      // [B, S] (start, end), clamped to NT
{
    const int b = blockIdx.x;
    const int t = threadIdx.x;

    __shared__ int cs[NS];
    cs[t] = d_src[b * NS + t];
    __syncthreads();
    #pragma unroll
    for (int off = 1; off < NS; off <<= 1) {
        int v = (t >= off) ? cs[t - off] : 0;
        __syncthreads();
        cs[t] += v;
        __syncthreads();
    }

    int end   = cs[t];
    int start = (t == 0) ? 0 : cs[t - 1];
    if (start > NT) start = NT;
    if (end   > NT) end   = NT;
    se[b * NS + t] = make_int2(start, end);
}

__global__ __launch_bounds__(256) void fs2_segmean_kernel(
    const float* __restrict__ e_src,  // [B, T, F, C]
    const int2*  __restrict__ se,     // [B, S]
    float*       __restrict__ out)    // [B, S, C]
{
    const int wave = threadIdx.x >> 6;           // 0..3: phone within block
    const int lane = threadIdx.x & 63;           // channel quad owner
    const int s    = blockIdx.x * 4 + wave;      // phone 0..255
    const int b    = blockIdx.y;                 // batch 0..31

    const int2 r    = se[b * NS + s];
    const int start = r.x;
    const int end   = r.y;

    // Frame slab [F=4][C=256] = 256 float4; freq f occupies float4 idx f*64..f*64+63.
    const float4* base = (const float4*)(e_src + (size_t)b * NT * NF * NC);

    float4 acc = make_float4(0.f, 0.f, 0.f, 0.f);
    for (int fr = start; fr < end; ++fr) {
        const float4* fb = base + (size_t)fr * (NF * NC / 4);
        #pragma unroll
        for (int f = 0; f < NF; ++f) {
            float4 v = fb[f * 64 + lane];   // 64 lanes x 16B contiguous
            acc.x += v.x; acc.y += v.y; acc.z += v.z; acc.w += v.w;
        }
    }

    const int cnt = end - start;
    const float inv = (cnt > 0) ? (1.0f / (4.0f * (float)cnt)) : 0.0f;
    float4 o;
    o.x = acc.x * inv; o.y = acc.y * inv; o.z = acc.z * inv; o.w = acc.w * inv;
    ((float4*)(out + ((size_t)b * NS + s) * NC))[lane] = o;
}

extern "C" void kernel_launch(void* const* d_in, const int* in_sizes, int n_in,
                              void* d_out, int out_size, void* d_ws, size_t ws_size,
                              hipStream_t stream) {
    const float* e_src = (const float*)d_in[0];
    const int*   d_src = (const int*)d_in[1];
    float*       out   = (float*)d_out;
    int2*        se    = (int2*)d_ws;   // 32*256*8 = 64 KB scratch

    fs2_scan_kernel<<<NB, NS, 0, stream>>>(d_src, se);

    dim3 grid(NS / 4, NB);   // 64 x 32 = 2048 blocks, one wave per phone
    fs2_segmean_kernel<<<grid, 256, 0, stream>>>(e_src, se, out);
}